// Round 5
// baseline (68.759 us; speedup 1.0000x reference)
//
#include <hip/hip_runtime.h>
#include <math.h>

// Bilateral filter, 5x5, reflect pad, sigma_spatial=2.0, sigma_range=0.1
// image: (16, 3, 512, 512) fp32 -> out same shape fp32.
//
// R5: TRANS-free weights. w = exp(-t), t = 50*(n-c)^2 + (dy^2+dx^2)/8,
// approximated by w = (1 - t/128)^128  (1 pk_fma + 7 pk_mul squarings).
// Max weight error ~2.1e-3 (at t~2), well under the 2e-2 threshold.
// All tap math is v_pk_*_f32 (2 pixels/op, 2 issue-cyc/wave64), zero
// v_exp_f32. u = fma(d^2, -0.390625, Bs), Bs = 1 - r2/1024 (both exact
// fp32); u in [0.60, 1] so no clamp and no underflow.
// Pixel pairing (px, px+4); raw (unscaled) pixels throughout.

#define IMG_H 512
#define IMG_W 512

typedef float v2f __attribute__((ext_vector_type(2)));

__device__ __forceinline__ float frcp(float x) {
    return __builtin_amdgcn_rcpf(x);    // v_rcp_f32
}

__device__ __forceinline__ v2f pk_add(v2f a, v2f b) {
    v2f r;
    asm("v_pk_add_f32 %0, %1, %2" : "=v"(r) : "v"(a), "v"(b));
    return r;
}
__device__ __forceinline__ v2f pk_mul(v2f a, v2f b) {
    v2f r;
    asm("v_pk_mul_f32 %0, %1, %2" : "=v"(r) : "v"(a), "v"(b));
    return r;
}
__device__ __forceinline__ v2f pk_fma(v2f a, v2f b, v2f c) {
    v2f r;
    asm("v_pk_fma_f32 %0, %1, %2, %3" : "=v"(r) : "v"(a), "v"(b), "v"(c));
    return r;
}
// fma with the addend held in an SGPR pair (per-tap spatial constant)
__device__ __forceinline__ v2f pk_fma_s(v2f a, v2f b, v2f c) {
    v2f r;
    asm("v_pk_fma_f32 %0, %1, %2, %3" : "=v"(r) : "v"(a), "v"(b), "s"(c));
    return r;
}

// acc += w*nn; nrm += w;  w = (Bs - 0.390625*d^2)^128, d = nn - c
__device__ __forceinline__ void tap(v2f& acc, v2f& nrm, v2f nn, v2f ncc,
                                    v2f vA, v2f bs) {
    v2f d = pk_add(nn, ncc);        // d = nn + (-c)
    v2f m = pk_mul(d, d);           // d^2
    v2f u = pk_fma_s(m, vA, bs);    // u = Bs - 0.390625*d^2  in [0.60, 1]
    u = pk_mul(u, u);               // u^2
    u = pk_mul(u, u);               // u^4
    u = pk_mul(u, u);               // u^8
    u = pk_mul(u, u);               // u^16
    u = pk_mul(u, u);               // u^32
    u = pk_mul(u, u);               // u^64
    u = pk_mul(u, u);               // u^128 ~= exp(-t)
    acc = pk_fma(u, nn, acc);       // acc += w * nn
    nrm = pk_add(nrm, u);           // nrm += w
}

// Each thread computes 8 contiguous x-pixels of one row of one (b,c) plane.
// tid bits: [5:0] = x-group (64 groups of 8) -> y,p wave-uniform,
//           [14:6] = y (512), [..:15] = plane (48 planes).
__global__ __launch_bounds__(256) void bilateral5x5_kernel(
        const float* __restrict__ img, float* __restrict__ out) {
    const int tid = blockIdx.x * 256 + threadIdx.x;
    const int xg = tid & 63;
    const int y  = (tid >> 6) & 511;
    const int p  = tid >> 15;

    const float* __restrict__ plane = img + (size_t)p * (IMG_H * IMG_W);
    float* __restrict__ oplane      = out + (size_t)p * (IMG_H * IMG_W);
    const int x0 = xg << 3;

    const v2f vA = {-0.390625f, -0.390625f};   // -50/128, exact

    // x-border (PAD=2): reflected cols land inside the central 8 ->
    // clamped in-bounds load addresses + 4 selects per row, no divergence.
    const bool xlo = (xg == 0);
    const bool xhi = (xg == 63);
    const int off_m0 = xlo ? x0 : (x0 - 4);
    const int off_m3 = xhi ? (x0 + 4) : (x0 + 8);

    // center pixels, negated (so d = pk_add(nn, ncc))
    const float4 c1 = *reinterpret_cast<const float4*>(plane + (size_t)y * IMG_W + x0);
    const float4 c2 = *reinterpret_cast<const float4*>(plane + (size_t)y * IMG_W + x0 + 4);
    v2f ncc[4];
    ncc[0] = (v2f){-c1.x, -c2.x};
    ncc[1] = (v2f){-c1.y, -c2.y};
    ncc[2] = (v2f){-c1.z, -c2.z};
    ncc[3] = (v2f){-c1.w, -c2.w};

    v2f acc[4] = {{0.f,0.f},{0.f,0.f},{0.f,0.f},{0.f,0.f}};
    v2f nrm[4] = {{0.f,0.f},{0.f,0.f},{0.f,0.f},{0.f,0.f}};

#pragma unroll
    for (int dy = -2; dy <= 2; ++dy) {
        int yy = y + dy;
        yy = (yy < 0) ? -yy : yy;                 // reflect top
        yy = (yy > 511) ? (1022 - yy) : yy;       // reflect bottom
        const float* __restrict__ row = plane + (size_t)yy * IMG_W;

        const float4 m0 = *reinterpret_cast<const float4*>(row + off_m0);
        const float4 m1 = *reinterpret_cast<const float4*>(row + x0);
        const float4 m2 = *reinterpret_cast<const float4*>(row + x0 + 4);
        const float4 m3 = *reinterpret_cast<const float4*>(row + off_m3);

        // window w[x0-2 .. x0+9]; pairs P[i] = {w[i-2], w[i+2]}
        const float w_m2 = xlo ? m1.z : m0.z;   // col -2 -> reflect col 2
        const float w_m1 = xlo ? m1.y : m0.w;   // col -1 -> reflect col 1
        const float w_8  = xhi ? m2.z : m3.x;   // col 512 -> reflect col 510
        const float w_9  = xhi ? m2.y : m3.y;   // col 513 -> reflect col 509

        v2f P[8];
        P[0] = (v2f){w_m2, m1.z};
        P[1] = (v2f){w_m1, m1.w};
        P[2] = (v2f){m1.x, m2.x};
        P[3] = (v2f){m1.y, m2.y};
        P[4] = (v2f){m1.z, m2.z};
        P[5] = (v2f){m1.w, m2.w};
        P[6] = (v2f){m2.x, w_8};
        P[7] = (v2f){m2.y, w_9};

#pragma unroll
        for (int dx = -2; dx <= 2; ++dx) {
            const float r2 = (float)(dy * dy + dx * dx);
            const float bsv = 1.0f - r2 * (1.0f / 1024.0f);  // exact fp32
            const v2f bs = {bsv, bsv};
#pragma unroll
            for (int pr = 0; pr < 4; ++pr) {
                const v2f nn = P[pr + dx + 2];
                if (dy == 0 && dx == 0) {
                    // center: w = 1 exactly
                    acc[pr] = pk_add(acc[pr], nn);
                    nrm[pr] = pk_add(nrm[pr], (v2f){1.0f, 1.0f});
                } else {
                    tap(acc[pr], nrm[pr], nn, ncc[pr], vA, bs);
                }
            }
        }
    }

    // out = acc / (nrm + 1e-8)
    float4 o1, o2;
    o1.x = acc[0].x * frcp(nrm[0].x + 1e-8f);
    o1.y = acc[1].x * frcp(nrm[1].x + 1e-8f);
    o1.z = acc[2].x * frcp(nrm[2].x + 1e-8f);
    o1.w = acc[3].x * frcp(nrm[3].x + 1e-8f);
    o2.x = acc[0].y * frcp(nrm[0].y + 1e-8f);
    o2.y = acc[1].y * frcp(nrm[1].y + 1e-8f);
    o2.z = acc[2].y * frcp(nrm[2].y + 1e-8f);
    o2.w = acc[3].y * frcp(nrm[3].y + 1e-8f);
    *reinterpret_cast<float4*>(oplane + (size_t)y * IMG_W + x0)     = o1;
    *reinterpret_cast<float4*>(oplane + (size_t)y * IMG_W + x0 + 4) = o2;
}

extern "C" void kernel_launch(void* const* d_in, const int* in_sizes, int n_in,
                              void* d_out, int out_size, void* d_ws, size_t ws_size,
                              hipStream_t stream) {
    const float* img = (const float*)d_in[0];
    float* out = (float*)d_out;

    const int n = in_sizes[0];                 // 16*3*512*512 = 12,582,912
    const int threads = n / 8;                 // 8 pixels per thread
    const int block = 256;
    const int grid = threads / block;          // 6144

    bilateral5x5_kernel<<<grid, block, 0, stream>>>(img, out);
}

// Round 6
// 64.116 us; speedup vs baseline: 1.0724x; 1.0724x over previous
//
#include <hip/hip_runtime.h>
#include <math.h>

// Bilateral filter, 5x5, reflect pad, sigma_spatial=2.0, sigma_range=0.1
// image: (16, 3, 512, 512) fp32 -> out same shape fp32.
//
// R6: TRANS-free weights in a FUSED asm block (R4 structure + R5 math).
// w = exp(-t), t = 50*d^2 + r2/8  approximated by  w = (1 - t/64)^64:
//   u = fma(d^2, -50/64, 1 - r2/512)   [-50/64 = -0.78125 exact,
//                                       1 - r2/512 exact for r2 in {1,2,4,5,8}]
//   w = u^64  (6 squarings). u in [0.203, 1] -> no clamp, no underflow.
// Max weight error e^-t*t^2/128 ~ 4.2e-3 (t=2) << 2e-2 threshold.
// Each asm block processes TWO pixel-pair taps with interleaved chains on
// hard temps v[0:1]/v[2:3] (halves dep-stall exposure, zero marshaling).
// R5's mistake (12 asm blocks/tap -> pair-marshal movs) is undone.

#define IMG_H 512
#define IMG_W 512

typedef float v2f __attribute__((ext_vector_type(2)));

__device__ __forceinline__ float frcp(float x) {
    return __builtin_amdgcn_rcpf(x);    // v_rcp_f32
}

__device__ __forceinline__ v2f pk_add(v2f a, v2f b) {
    v2f r;
    asm("v_pk_add_f32 %0, %1, %2" : "=v"(r) : "v"(a), "v"(b));
    return r;
}

// Two taps (pixel-pairs A,B) fused:
//   dX = nnX + nccX; uX = fma(dX^2, vA, bs); wX = uX^64;
//   accX += wX*nnX; nrmX += wX;
__device__ __forceinline__ void tap2(v2f& accA, v2f& nrmA, v2f& accB, v2f& nrmB,
                                     v2f nnA, v2f nnB, v2f nccA, v2f nccB,
                                     v2f vA, v2f bs) {
    asm("v_pk_add_f32 v[0:1], %4, %6\n\t"              // dA
        "v_pk_add_f32 v[2:3], %5, %7\n\t"              // dB
        "v_pk_mul_f32 v[0:1], v[0:1], v[0:1]\n\t"      // dA^2
        "v_pk_mul_f32 v[2:3], v[2:3], v[2:3]\n\t"      // dB^2
        "v_pk_fma_f32 v[0:1], v[0:1], %8, %9\n\t"      // uA = bs - 0.78125*dA^2
        "v_pk_fma_f32 v[2:3], v[2:3], %8, %9\n\t"      // uB
        "v_pk_mul_f32 v[0:1], v[0:1], v[0:1]\n\t"      // uA^2
        "v_pk_mul_f32 v[2:3], v[2:3], v[2:3]\n\t"
        "v_pk_mul_f32 v[0:1], v[0:1], v[0:1]\n\t"      // uA^4
        "v_pk_mul_f32 v[2:3], v[2:3], v[2:3]\n\t"
        "v_pk_mul_f32 v[0:1], v[0:1], v[0:1]\n\t"      // uA^8
        "v_pk_mul_f32 v[2:3], v[2:3], v[2:3]\n\t"
        "v_pk_mul_f32 v[0:1], v[0:1], v[0:1]\n\t"      // uA^16
        "v_pk_mul_f32 v[2:3], v[2:3], v[2:3]\n\t"
        "v_pk_mul_f32 v[0:1], v[0:1], v[0:1]\n\t"      // uA^32
        "v_pk_mul_f32 v[2:3], v[2:3], v[2:3]\n\t"
        "v_pk_mul_f32 v[0:1], v[0:1], v[0:1]\n\t"      // uA^64 = wA
        "v_pk_mul_f32 v[2:3], v[2:3], v[2:3]\n\t"      // uB^64 = wB
        "v_pk_fma_f32 %0, v[0:1], %4, %0\n\t"          // accA += wA*nnA
        "v_pk_fma_f32 %2, v[2:3], %5, %2\n\t"          // accB += wB*nnB
        "v_pk_add_f32 %1, %1, v[0:1]\n\t"              // nrmA += wA
        "v_pk_add_f32 %3, %3, v[2:3]"                  // nrmB += wB
        : "+v"(accA), "+v"(nrmA), "+v"(accB), "+v"(nrmB)
        : "v"(nnA), "v"(nnB), "v"(nccA), "v"(nccB), "v"(vA), "s"(bs)
        : "v0", "v1", "v2", "v3");
}

// Each thread computes 8 contiguous x-pixels of one row of one (b,c) plane.
// Pixel pairing (px, px+4). tid bits: [5:0] = x-group (64 groups of 8),
// [14:6] = y (512), [..:15] = plane (48).
__global__ __launch_bounds__(256) void bilateral5x5_kernel(
        const float* __restrict__ img, float* __restrict__ out) {
    const int tid = blockIdx.x * 256 + threadIdx.x;
    const int xg = tid & 63;
    const int y  = (tid >> 6) & 511;
    const int p  = tid >> 15;

    const float* __restrict__ plane = img + (size_t)p * (IMG_H * IMG_W);
    float* __restrict__ oplane      = out + (size_t)p * (IMG_H * IMG_W);
    const int x0 = xg << 3;

    const v2f vA = {-0.78125f, -0.78125f};   // -50/64, exact

    // x-border (PAD=2): reflected cols land inside the central 8 ->
    // clamped in-bounds load addresses + 4 selects per row, no divergence.
    const bool xlo = (xg == 0);
    const bool xhi = (xg == 63);
    const int off_m0 = xlo ? x0 : (x0 - 4);
    const int off_m3 = xhi ? (x0 + 4) : (x0 + 8);

    // center pixels, negated (so d = pk_add(nn, ncc))
    const float4 c1 = *reinterpret_cast<const float4*>(plane + (size_t)y * IMG_W + x0);
    const float4 c2 = *reinterpret_cast<const float4*>(plane + (size_t)y * IMG_W + x0 + 4);
    v2f ncc[4];
    ncc[0] = (v2f){-c1.x, -c2.x};
    ncc[1] = (v2f){-c1.y, -c2.y};
    ncc[2] = (v2f){-c1.z, -c2.z};
    ncc[3] = (v2f){-c1.w, -c2.w};

    v2f acc[4] = {{0.f,0.f},{0.f,0.f},{0.f,0.f},{0.f,0.f}};
    v2f nrm[4] = {{0.f,0.f},{0.f,0.f},{0.f,0.f},{0.f,0.f}};

#pragma unroll
    for (int dy = -2; dy <= 2; ++dy) {
        int yy = y + dy;
        yy = (yy < 0) ? -yy : yy;                 // reflect top
        yy = (yy > 511) ? (1022 - yy) : yy;       // reflect bottom
        const float* __restrict__ row = plane + (size_t)yy * IMG_W;

        const float4 m0 = *reinterpret_cast<const float4*>(row + off_m0);
        const float4 m1 = *reinterpret_cast<const float4*>(row + x0);
        const float4 m2 = *reinterpret_cast<const float4*>(row + x0 + 4);
        const float4 m3 = *reinterpret_cast<const float4*>(row + off_m3);

        // window w[x0-2 .. x0+9]; pairs P[i] = {w[i-2], w[i+2]}
        const float w_m2 = xlo ? m1.z : m0.z;   // col -2 -> reflect col 2
        const float w_m1 = xlo ? m1.y : m0.w;   // col -1 -> reflect col 1
        const float w_8  = xhi ? m2.z : m3.x;   // col 512 -> reflect col 510
        const float w_9  = xhi ? m2.y : m3.y;   // col 513 -> reflect col 509

        v2f P[8];
        P[0] = (v2f){w_m2, m1.z};
        P[1] = (v2f){w_m1, m1.w};
        P[2] = (v2f){m1.x, m2.x};
        P[3] = (v2f){m1.y, m2.y};
        P[4] = (v2f){m1.z, m2.z};
        P[5] = (v2f){m1.w, m2.w};
        P[6] = (v2f){m2.x, w_8};
        P[7] = (v2f){m2.y, w_9};

#pragma unroll
        for (int dx = -2; dx <= 2; ++dx) {
            const float r2 = (float)(dy * dy + dx * dx);
            const float bsv = 1.0f - r2 * (1.0f / 512.0f);  // exact fp32
            const v2f bs = {bsv, bsv};
            if (dy == 0 && dx == 0) {
                // center: w = 1 exactly
#pragma unroll
                for (int pr = 0; pr < 4; ++pr) {
                    acc[pr] = pk_add(acc[pr], P[pr + 2]);
                    nrm[pr] = pk_add(nrm[pr], (v2f){1.0f, 1.0f});
                }
            } else {
                tap2(acc[0], nrm[0], acc[1], nrm[1],
                     P[dx + 2], P[dx + 3], ncc[0], ncc[1], vA, bs);
                tap2(acc[2], nrm[2], acc[3], nrm[3],
                     P[dx + 4], P[dx + 5], ncc[2], ncc[3], vA, bs);
            }
        }
    }

    // out = acc / (nrm + 1e-8)
    float4 o1, o2;
    o1.x = acc[0].x * frcp(nrm[0].x + 1e-8f);
    o1.y = acc[1].x * frcp(nrm[1].x + 1e-8f);
    o1.z = acc[2].x * frcp(nrm[2].x + 1e-8f);
    o1.w = acc[3].x * frcp(nrm[3].x + 1e-8f);
    o2.x = acc[0].y * frcp(nrm[0].y + 1e-8f);
    o2.y = acc[1].y * frcp(nrm[1].y + 1e-8f);
    o2.z = acc[2].y * frcp(nrm[2].y + 1e-8f);
    o2.w = acc[3].y * frcp(nrm[3].y + 1e-8f);
    *reinterpret_cast<float4*>(oplane + (size_t)y * IMG_W + x0)     = o1;
    *reinterpret_cast<float4*>(oplane + (size_t)y * IMG_W + x0 + 4) = o2;
}

extern "C" void kernel_launch(void* const* d_in, const int* in_sizes, int n_in,
                              void* d_out, int out_size, void* d_ws, size_t ws_size,
                              hipStream_t stream) {
    const float* img = (const float*)d_in[0];
    float* out = (float*)d_out;

    const int n = in_sizes[0];                 // 16*3*512*512 = 12,582,912
    const int threads = n / 8;                 // 8 pixels per thread
    const int block = 256;
    const int grid = threads / block;          // 6144

    bilateral5x5_kernel<<<grid, block, 0, stream>>>(img, out);
}

// Round 8
// 62.423 us; speedup vs baseline: 1.1015x; 1.0271x over previous
//
#include <hip/hip_runtime.h>
#include <math.h>

// Bilateral filter, 5x5, reflect pad, sigma_spatial=2.0, sigma_range=0.1
// image: (16, 3, 512, 512) fp32 -> out same shape fp32.
//
// R8 = R7 with the cvt_pkrtz return-type fix (__fp16 vector, not _Float16).
// Packed-f16 weight chain (v_pk_*_f16 double-rate: 2 cyc/wave64 vs 4 for
// v_pk_*_f32). Issue model: scalar f32 = 2, pk f32 = 4, pk f16 = 2, exp ~8.
// w = (1 - t/64)^64, t = 50*d^2 + r2/8:
//   window & center prescaled by SA = sqrt(50/64) (f32 mul, then cvt_pkrtz
//   to f16 pairs; pairing (px, px+4) -> 1 cvt per pair per row)
//   u' = pk_fma_f16(d, d, nbs) = d^2 - bs   (nbs = -(1 - r2/512), EXACT f16)
//   first squaring kills the sign -> zero src modifiers needed
//   6x pk_mul_f16 -> u^64 = w (f16)
//   v_fma_mix_f32: acc += w(f16)*nn(f16) in f32; nrm += w*1.0 in f32
// Per tap-pair: 12 instrs x 2 cyc = 24 cyc vs R4's 32 (exp) / R6's 44.
// One asm block per (dy,dx): 4 interleaved chains on v0-v3, no marshaling.
// Center tap: w=1 -> nrm init = 1.0, acc += nn via 8 mix instrs.

#define IMG_H 512
#define IMG_W 512

__device__ __forceinline__ float frcp(float x) {
    return __builtin_amdgcn_rcpf(x);    // v_rcp_f32
}

// pack two f32 -> f16x2 (round toward zero), bits held in a float
__device__ __forceinline__ float cvtpk(float lo, float hi) {
    auto h = __builtin_amdgcn_cvt_pkrtz(lo, hi);  // __fp16 ext_vector(2)
    return __builtin_bit_cast(float, h);
}

// -(1 - r2/512) as f16x2 bits (all exactly representable)
__device__ __forceinline__ float nbs_f(int r2) {
    unsigned h = (r2 == 1) ? 0xBBFCu
               : (r2 == 2) ? 0xBBF8u
               : (r2 == 4) ? 0xBBF0u
               : (r2 == 5) ? 0xBBECu
               :             0xBBE0u;   // r2 == 8
    return __builtin_bit_cast(float, h | (h << 16));
}

// Four tap-pairs for one (dy,dx): chains on v0..v3.
// p{c} = f16x2 {SA*n[px=c], SA*n[px=c+4]}, q{c} = f16x2 {-SA*c[c], -SA*c[c+4]}
// u = (d^2 - bs); w = u^64 (sign dies at first squaring);
// acc(f32) += w*nn (both f16 via fma_mix); nrm(f32) += w.
__device__ __forceinline__ void tap4(
        float& a0, float& a1, float& a2, float& a3,
        float& a4, float& a5, float& a6, float& a7,
        float& n0, float& n1, float& n2, float& n3,
        float& n4, float& n5, float& n6, float& n7,
        float p0, float p1, float p2, float p3,
        float q0, float q1, float q2, float q3,
        float nbs) {
    asm("v_pk_add_f16 v0, %16, %20\n\t"
        "v_pk_add_f16 v1, %17, %21\n\t"
        "v_pk_add_f16 v2, %18, %22\n\t"
        "v_pk_add_f16 v3, %19, %23\n\t"
        "v_pk_fma_f16 v0, v0, v0, %24\n\t"
        "v_pk_fma_f16 v1, v1, v1, %24\n\t"
        "v_pk_fma_f16 v2, v2, v2, %24\n\t"
        "v_pk_fma_f16 v3, v3, v3, %24\n\t"
        "v_pk_mul_f16 v0, v0, v0\n\t"   // u^2 (sign gone)
        "v_pk_mul_f16 v1, v1, v1\n\t"
        "v_pk_mul_f16 v2, v2, v2\n\t"
        "v_pk_mul_f16 v3, v3, v3\n\t"
        "v_pk_mul_f16 v0, v0, v0\n\t"   // u^4
        "v_pk_mul_f16 v1, v1, v1\n\t"
        "v_pk_mul_f16 v2, v2, v2\n\t"
        "v_pk_mul_f16 v3, v3, v3\n\t"
        "v_pk_mul_f16 v0, v0, v0\n\t"   // u^8
        "v_pk_mul_f16 v1, v1, v1\n\t"
        "v_pk_mul_f16 v2, v2, v2\n\t"
        "v_pk_mul_f16 v3, v3, v3\n\t"
        "v_pk_mul_f16 v0, v0, v0\n\t"   // u^16
        "v_pk_mul_f16 v1, v1, v1\n\t"
        "v_pk_mul_f16 v2, v2, v2\n\t"
        "v_pk_mul_f16 v3, v3, v3\n\t"
        "v_pk_mul_f16 v0, v0, v0\n\t"   // u^32
        "v_pk_mul_f16 v1, v1, v1\n\t"
        "v_pk_mul_f16 v2, v2, v2\n\t"
        "v_pk_mul_f16 v3, v3, v3\n\t"
        "v_pk_mul_f16 v0, v0, v0\n\t"   // u^64 = w
        "v_pk_mul_f16 v1, v1, v1\n\t"
        "v_pk_mul_f16 v2, v2, v2\n\t"
        "v_pk_mul_f16 v3, v3, v3\n\t"
        "v_fma_mix_f32 %0, v0, %16, %0 op_sel:[0,0,0] op_sel_hi:[1,1,0]\n\t"
        "v_fma_mix_f32 %1, v1, %17, %1 op_sel:[0,0,0] op_sel_hi:[1,1,0]\n\t"
        "v_fma_mix_f32 %2, v2, %18, %2 op_sel:[0,0,0] op_sel_hi:[1,1,0]\n\t"
        "v_fma_mix_f32 %3, v3, %19, %3 op_sel:[0,0,0] op_sel_hi:[1,1,0]\n\t"
        "v_fma_mix_f32 %4, v0, %16, %4 op_sel:[1,1,0] op_sel_hi:[1,1,0]\n\t"
        "v_fma_mix_f32 %5, v1, %17, %5 op_sel:[1,1,0] op_sel_hi:[1,1,0]\n\t"
        "v_fma_mix_f32 %6, v2, %18, %6 op_sel:[1,1,0] op_sel_hi:[1,1,0]\n\t"
        "v_fma_mix_f32 %7, v3, %19, %7 op_sel:[1,1,0] op_sel_hi:[1,1,0]\n\t"
        "v_fma_mix_f32 %8, v0, 1.0, %8 op_sel:[0,0,0] op_sel_hi:[1,0,0]\n\t"
        "v_fma_mix_f32 %9, v1, 1.0, %9 op_sel:[0,0,0] op_sel_hi:[1,0,0]\n\t"
        "v_fma_mix_f32 %10, v2, 1.0, %10 op_sel:[0,0,0] op_sel_hi:[1,0,0]\n\t"
        "v_fma_mix_f32 %11, v3, 1.0, %11 op_sel:[0,0,0] op_sel_hi:[1,0,0]\n\t"
        "v_fma_mix_f32 %12, v0, 1.0, %12 op_sel:[1,0,0] op_sel_hi:[1,0,0]\n\t"
        "v_fma_mix_f32 %13, v1, 1.0, %13 op_sel:[1,0,0] op_sel_hi:[1,0,0]\n\t"
        "v_fma_mix_f32 %14, v2, 1.0, %14 op_sel:[1,0,0] op_sel_hi:[1,0,0]\n\t"
        "v_fma_mix_f32 %15, v3, 1.0, %15 op_sel:[1,0,0] op_sel_hi:[1,0,0]"
        : "+v"(a0), "+v"(a1), "+v"(a2), "+v"(a3),
          "+v"(a4), "+v"(a5), "+v"(a6), "+v"(a7),
          "+v"(n0), "+v"(n1), "+v"(n2), "+v"(n3),
          "+v"(n4), "+v"(n5), "+v"(n6), "+v"(n7)
        : "v"(p0), "v"(p1), "v"(p2), "v"(p3),
          "v"(q0), "v"(q1), "v"(q2), "v"(q3),
          "v"(nbs)
        : "v0", "v1", "v2", "v3");
}

// center tap: w = 1 exactly; acc += nn (nrm handled by init = 1.0)
__device__ __forceinline__ void center4(
        float& a0, float& a1, float& a2, float& a3,
        float& a4, float& a5, float& a6, float& a7,
        float p0, float p1, float p2, float p3) {
    asm("v_fma_mix_f32 %0, %8, 1.0, %0 op_sel:[0,0,0] op_sel_hi:[1,0,0]\n\t"
        "v_fma_mix_f32 %1, %9, 1.0, %1 op_sel:[0,0,0] op_sel_hi:[1,0,0]\n\t"
        "v_fma_mix_f32 %2, %10, 1.0, %2 op_sel:[0,0,0] op_sel_hi:[1,0,0]\n\t"
        "v_fma_mix_f32 %3, %11, 1.0, %3 op_sel:[0,0,0] op_sel_hi:[1,0,0]\n\t"
        "v_fma_mix_f32 %4, %8, 1.0, %4 op_sel:[1,0,0] op_sel_hi:[1,0,0]\n\t"
        "v_fma_mix_f32 %5, %9, 1.0, %5 op_sel:[1,0,0] op_sel_hi:[1,0,0]\n\t"
        "v_fma_mix_f32 %6, %10, 1.0, %6 op_sel:[1,0,0] op_sel_hi:[1,0,0]\n\t"
        "v_fma_mix_f32 %7, %11, 1.0, %7 op_sel:[1,0,0] op_sel_hi:[1,0,0]"
        : "+v"(a0), "+v"(a1), "+v"(a2), "+v"(a3),
          "+v"(a4), "+v"(a5), "+v"(a6), "+v"(a7)
        : "v"(p0), "v"(p1), "v"(p2), "v"(p3));
}

// Each thread computes 8 contiguous x-pixels of one row of one (b,c) plane.
// Pixel pairing (px, px+4). tid bits: [5:0] = x-group (64 groups of 8),
// [14:6] = y (512), [..:15] = plane (48).
__global__ __launch_bounds__(256) void bilateral5x5_kernel(
        const float* __restrict__ img, float* __restrict__ out) {
    const int tid = blockIdx.x * 256 + threadIdx.x;
    const int xg = tid & 63;
    const int y  = (tid >> 6) & 511;
    const int p  = tid >> 15;

    const float* __restrict__ plane = img + (size_t)p * (IMG_H * IMG_W);
    float* __restrict__ oplane      = out + (size_t)p * (IMG_H * IMG_W);
    const int x0 = xg << 3;

    const float SA = 0.8838834764831844f;   // sqrt(50/64), f32

    // x-border (PAD=2): reflected cols land inside the central 8 ->
    // clamped in-bounds load addresses + 4 selects per row, no divergence.
    const bool xlo = (xg == 0);
    const bool xhi = (xg == 63);
    const int off_m0 = xlo ? x0 : (x0 - 4);
    const int off_m3 = xhi ? (x0 + 4) : (x0 + 8);

    // center pixels -> f16x2 pairs of -SA*c
    const float4 c1 = *reinterpret_cast<const float4*>(plane + (size_t)y * IMG_W + x0);
    const float4 c2 = *reinterpret_cast<const float4*>(plane + (size_t)y * IMG_W + x0 + 4);
    const float q0 = cvtpk(-SA * c1.x, -SA * c2.x);
    const float q1 = cvtpk(-SA * c1.y, -SA * c2.y);
    const float q2 = cvtpk(-SA * c1.z, -SA * c2.z);
    const float q3 = cvtpk(-SA * c1.w, -SA * c2.w);

    float a0 = 0.f, a1 = 0.f, a2 = 0.f, a3 = 0.f;
    float a4 = 0.f, a5 = 0.f, a6 = 0.f, a7 = 0.f;
    // nrm init = 1.0 accounts for the center tap's weight
    float n0 = 1.f, n1 = 1.f, n2 = 1.f, n3 = 1.f;
    float n4 = 1.f, n5 = 1.f, n6 = 1.f, n7 = 1.f;

#pragma unroll
    for (int dy = -2; dy <= 2; ++dy) {
        int yy = y + dy;
        yy = (yy < 0) ? -yy : yy;                 // reflect top
        yy = (yy > 511) ? (1022 - yy) : yy;       // reflect bottom
        const float* __restrict__ row = plane + (size_t)yy * IMG_W;

        const float4 m0 = *reinterpret_cast<const float4*>(row + off_m0);
        const float4 m1 = *reinterpret_cast<const float4*>(row + x0);
        const float4 m2 = *reinterpret_cast<const float4*>(row + x0 + 4);
        const float4 m3 = *reinterpret_cast<const float4*>(row + off_m3);

        // window cols x0-2 .. x0+9 (f32, border-reflected via selects)
        const float w_m2 = xlo ? m1.z : m0.z;   // col -2 -> reflect col 2
        const float w_m1 = xlo ? m1.y : m0.w;   // col -1 -> reflect col 1
        const float w_8  = xhi ? m2.z : m3.x;   // col 512 -> reflect col 510
        const float w_9  = xhi ? m2.y : m3.y;   // col 513 -> reflect col 509

        // scale by SA in f32, pack pairs {col k, col k+4} to f16x2
        const float s0  = SA * w_m2, s1 = SA * w_m1;
        const float s2  = SA * m1.x, s3 = SA * m1.y;
        const float s4  = SA * m1.z, s5 = SA * m1.w;
        const float s6  = SA * m2.x, s7 = SA * m2.y;
        const float s8  = SA * m2.z, s9 = SA * m2.w;
        const float s10 = SA * w_8,  s11 = SA * w_9;

        float P[8];
        P[0] = cvtpk(s0, s4);
        P[1] = cvtpk(s1, s5);
        P[2] = cvtpk(s2, s6);
        P[3] = cvtpk(s3, s7);
        P[4] = cvtpk(s4, s8);
        P[5] = cvtpk(s5, s9);
        P[6] = cvtpk(s6, s10);
        P[7] = cvtpk(s7, s11);

#pragma unroll
        for (int dx = -2; dx <= 2; ++dx) {
            if (dy == 0 && dx == 0) {
                center4(a0, a1, a2, a3, a4, a5, a6, a7,
                        P[2], P[3], P[4], P[5]);
            } else {
                tap4(a0, a1, a2, a3, a4, a5, a6, a7,
                     n0, n1, n2, n3, n4, n5, n6, n7,
                     P[dx + 2], P[dx + 3], P[dx + 4], P[dx + 5],
                     q0, q1, q2, q3,
                     nbs_f(dy * dy + dx * dx));
            }
        }
    }

    // acc = SA * sum(w*n) (f16-scaled); out = acc * rcp(SA*nrm + SA*1e-8)
    const float Seps = SA * 1e-8f;
    float4 o1, o2;
    o1.x = a0 * frcp(fmaf(n0, SA, Seps));
    o1.y = a1 * frcp(fmaf(n1, SA, Seps));
    o1.z = a2 * frcp(fmaf(n2, SA, Seps));
    o1.w = a3 * frcp(fmaf(n3, SA, Seps));
    o2.x = a4 * frcp(fmaf(n4, SA, Seps));
    o2.y = a5 * frcp(fmaf(n5, SA, Seps));
    o2.z = a6 * frcp(fmaf(n6, SA, Seps));
    o2.w = a7 * frcp(fmaf(n7, SA, Seps));
    *reinterpret_cast<float4*>(oplane + (size_t)y * IMG_W + x0)     = o1;
    *reinterpret_cast<float4*>(oplane + (size_t)y * IMG_W + x0 + 4) = o2;
}

extern "C" void kernel_launch(void* const* d_in, const int* in_sizes, int n_in,
                              void* d_out, int out_size, void* d_ws, size_t ws_size,
                              hipStream_t stream) {
    const float* img = (const float*)d_in[0];
    float* out = (float*)d_out;

    const int n = in_sizes[0];                 // 16*3*512*512 = 12,582,912
    const int threads = n / 8;                 // 8 pixels per thread
    const int block = 256;
    const int grid = threads / block;          // 6144

    bilateral5x5_kernel<<<grid, block, 0, stream>>>(img, out);
}